// Round 21
// baseline (186.630 us; speedup 1.0000x reference)
//
#include <hip/hip_runtime.h>
#include <hip/hip_bf16.h>

#define N_B 4
#define SEQ 2048
#define EMB 1024
#define NH  16
#define HD  64
#define NT  (SEQ / 64)

typedef __attribute__((ext_vector_type(8))) short bf16x8;   // 8 bf16 in 4 VGPRs
typedef __attribute__((ext_vector_type(4))) short bf16x4;   // 4 bf16 in 2 VGPRs
typedef __attribute__((ext_vector_type(4))) float f32x4;
typedef unsigned int u32;
typedef unsigned long long u64;
typedef unsigned short u16;

__device__ __forceinline__ void load_lds_16B(const void* g, void* lds) {
  __builtin_amdgcn_global_load_lds(
      (const __attribute__((address_space(1))) u32*)g,
      (__attribute__((address_space(3))) u32*)lds, 16, 0, 0);
}

// pack two f32 -> two bf16 (round-to-nearest via +0x8000 before truncate)
__device__ __forceinline__ u32 pk2(float a, float b) {
  u32 au = __float_as_uint(a) + 0x8000u;
  u32 bu = __float_as_uint(b) + 0x8000u;
  return (au >> 16) | (bu & 0xFFFF0000u);
}

__device__ __forceinline__ float m3(float a, float b, float c) {
  return fmaxf(fmaxf(a, b), c);   // clang fuses to v_max3_f32
}

// ---------------- unified MFMA pre-pass (R19-proven) ----------------
// grid (32, 16, 17):
//   z in [0,4): mask->bitmask pack, 2048 blocks x 4 rows (batched-load TLP).
//   z == 4: Wo fp32->bf16 cvt.
//   z in [5,17): projection, which = (z-5)>>2 (0=v,1=k,2=q), n = (z-5)&3.
__global__ __launch_bounds__(256) void fused_pre_k(const float* __restrict__ xv,
                                                   const float* __restrict__ xk,
                                                   const float* __restrict__ xq,
                                                   const float* __restrict__ Wv,
                                                   const float* __restrict__ Wk,
                                                   const float* __restrict__ Wq,
                                                   __hip_bfloat16* __restrict__ vT,
                                                   __hip_bfloat16* __restrict__ kp,
                                                   __hip_bfloat16* __restrict__ qp,
                                                   const int* __restrict__ mask,
                                                   u64* __restrict__ bits,
                                                   const float* __restrict__ Wo,
                                                   __hip_bfloat16* __restrict__ wob,
                                                   float qscale) {
  int z = blockIdx.z;
  int t = threadIdx.x;
  if (z < 4) {                         // ---- mask pack (4 rows, batched loads)
    int flat = (z * 16 + blockIdx.y) * 32 + blockIdx.x;   // 0..2047
    int lane = t & 63, wv = t >> 6;
    int row0 = flat * 4;
    for (int w = wv; w < 32; w += 4) {
      int v0 = mask[(size_t)(row0 + 0) * SEQ + w * 64 + lane];
      int v1 = mask[(size_t)(row0 + 1) * SEQ + w * 64 + lane];
      int v2 = mask[(size_t)(row0 + 2) * SEQ + w * 64 + lane];
      int v3 = mask[(size_t)(row0 + 3) * SEQ + w * 64 + lane];
      u64 b0 = __ballot(v0 != 0);
      u64 b1 = __ballot(v1 != 0);
      u64 b2 = __ballot(v2 != 0);
      u64 b3 = __ballot(v3 != 0);
      if (lane == 0) {
        int n = row0 >> 11;                       // 4 rows never straddle n
        size_t base = ((size_t)n * 32 + w) * 2048 + (row0 & 2047);
        bits[base + 0] = b0;
        bits[base + 1] = b1;
        bits[base + 2] = b2;
        bits[base + 3] = b3;
      }
    }
    return;
  }
  if (z == 4) {                        // ---- Wo cvt
    int flat = blockIdx.y * 32 + blockIdx.x;   // 0..511
#pragma unroll
    for (int k = 0; k < 2; ++k) {
      int f4i = flat * 512 + k * 256 + t;
      float4 v = ((const float4*)Wo)[f4i];
      int i = f4i * 4;
      wob[i + 0] = __float2bfloat16(v.x);
      wob[i + 1] = __float2bfloat16(v.y);
      wob[i + 2] = __float2bfloat16(v.z);
      wob[i + 3] = __float2bfloat16(v.w);
    }
    return;
  }
  // ---- projection
  int zz = z - 5;
  int which = zz >> 2, n = zz & 3;
  int kt = blockIdx.x, h = blockIdx.y;
  const float* x = (which == 0) ? xv : (which == 1) ? xk : xq;
  const float* W = (which == 0) ? Wv : (which == 1) ? Wk : Wq;
  float wscale = (which == 2) ? qscale : 1.0f;
  __shared__ __align__(16) __hip_bfloat16 Xs[64 * 64];   // [row][dd] chunk-swz
  __shared__ __align__(16) __hip_bfloat16 Ws[64 * 64];   // [d][dd]   chunk-swz

  int tr = t >> 4, c4 = t & 15;
  const float4* x4 = (const float4*)x;
#pragma unroll
  for (int i = 0; i < 4; ++i) {
    int r = i * 16 + tr;
    float4 v = x4[((size_t)(n * SEQ + kt * 64 + r)) * 256 + h * 16 + c4];
    uint2 pv = {pk2(v.x, v.y), pk2(v.z, v.w)};
    *(uint2*)((char*)Xs + r * 128 + (((c4 >> 1) ^ (r & 7)) * 16) + (c4 & 1) * 8) = pv;
  }
  const float4* W4 = (const float4*)W;
#pragma unroll
  for (int i = 0; i < 4; ++i) {
    int d = i * 16 + tr, dd4 = c4;
    float4 v = W4[(size_t)d * 16 + dd4];
    uint2 pv = {pk2(v.x * wscale, v.y * wscale), pk2(v.z * wscale, v.w * wscale)};
    *(uint2*)((char*)Ws + d * 128 + (((dd4 >> 1) ^ (d & 7)) * 16) + (dd4 & 1) * 8) = pv;
  }
  __syncthreads();

  int lane = t & 63, w = t >> 6;
  int l15 = lane & 15, l4 = lane >> 4, e7 = l15 & 7;
  bf16x8 xa0 = *(const bf16x8*)((char*)Xs + (w * 16 + l15) * 128 + ((l4 ^ e7) * 16));
  bf16x8 xa1 = *(const bf16x8*)((char*)Xs + (w * 16 + l15) * 128 + (((4 + l4) ^ e7) * 16));
  if (which == 0) {
    // ---- V: D[seq][d]; packed uint2 store per dt into vT granule-perm layout
    u16* dst = (u16*)(vT + (size_t)(n * NH + h) * HD * SEQ);
#pragma unroll
    for (int dt = 0; dt < 4; ++dt) {
      bf16x8 wb0 = *(const bf16x8*)((char*)Ws + (dt * 16 + l15) * 128 + ((l4 ^ e7) * 16));
      bf16x8 wb1 = *(const bf16x8*)((char*)Ws + (dt * 16 + l15) * 128 + (((4 + l4) ^ e7) * 16));
      f32x4 c = {0.f, 0.f, 0.f, 0.f};
      c = __builtin_amdgcn_mfma_f32_16x16x32_bf16(xa0, wb0, c, 0, 0, 0);
      c = __builtin_amdgcn_mfma_f32_16x16x32_bf16(xa1, wb1, c, 0, 0, 0);
      int d = dt * 16 + l15;
      int slotbase = kt * 64 + (((w * 4 + l4) ^ l15) * 4);
      uint2 pv = {pk2(c[0], c[1]), pk2(c[2], c[3])};
      *(uint2*)(dst + (size_t)d * SEQ + slotbase) = pv;
    }
  } else {
    // ---- K/Q: swapped operands -> D[d][seq]; packed uint2 store per dt
    __hip_bfloat16* out = (which == 1) ? kp : qp;
    u16* orow = (u16*)(out + ((size_t)(n * NH + h) * SEQ + kt * 64 + w * 16 + l15) * HD);
#pragma unroll
    for (int dt = 0; dt < 4; ++dt) {
      bf16x8 wb0 = *(const bf16x8*)((char*)Ws + (dt * 16 + l15) * 128 + ((l4 ^ e7) * 16));
      bf16x8 wb1 = *(const bf16x8*)((char*)Ws + (dt * 16 + l15) * 128 + (((4 + l4) ^ e7) * 16));
      f32x4 c = {0.f, 0.f, 0.f, 0.f};
      c = __builtin_amdgcn_mfma_f32_16x16x32_bf16(wb0, xa0, c, 0, 0, 0);
      c = __builtin_amdgcn_mfma_f32_16x16x32_bf16(wb1, xa1, c, 0, 0, 0);
      uint2 pv = {pk2(c[0], c[1]), pk2(c[2], c[3])};
      *(uint2*)(orow + dt * 16 + l4 * 4) = pv;
    }
  }
}

// ---------------- flash attention (16-wave blocks, QBLK=256) ----------------
// Same per-wave structure; 16 waves share each staged K/V tile. Waves 0-7
// stage K, waves 8-15 stage V (1 global_load_lds per thread). LDS 32KB dbuf
// -> 2 blocks/CU = 32 waves/CU (hardware max).
__global__ __launch_bounds__(1024) void attn_k(const __hip_bfloat16* __restrict__ qp,
                                               const __hip_bfloat16* __restrict__ kp,
                                               const __hip_bfloat16* __restrict__ vT,
                                               const u64* __restrict__ mbits,
                                               __hip_bfloat16* __restrict__ obuf) {
  __shared__ __align__(16) __hip_bfloat16 Kt[2][64 * 64];    // [key][kdim] chunk-swz
  __shared__ __align__(16) __hip_bfloat16 Vt[2][64 * 64];    // [d][key] granule-swz
  int t = threadIdx.x, lane = t & 63, w = t >> 6;            // w in [0,16)
  // XCD swizzle (bijective rotation; XCD a -> heads [8a, 8a+8))
  int flat = blockIdx.y * 8 + blockIdx.x;                    // 0..511
  int nf = (flat & 7) * 64 + (flat >> 3);
  int qb = nf & 7, nh = nf >> 3;                             // qb: 256-row block
  int n = nh >> 4, h = nh & 15;
  const __hip_bfloat16* Qg = qp + ((size_t)nh * SEQ + qb * 256) * HD;
  const char* Kg = (const char*)(kp + (size_t)nh * SEQ * HD);
  const char* Vg = (const char*)(vT + (size_t)nh * HD * SEQ);
  int l15 = lane & 15, l4 = lane >> 4;
  int e7 = l15 & 7;

  // staging: threads 0..511 (waves 0-7) stage K; 512..1023 (waves 8-15) stage V
  int ts = t & 511;
  int srow = ts >> 3;                      // 0..63
  int schunk = (ts & 7) ^ (srow & 7);      // K pre-swizzle (V is linear: pre-permuted)
  const char* gk0 = Kg + srow * 128 + schunk * 16;            // + kt*8192
  const char* gv0 = Vg + (size_t)srow * 4096 + (ts & 7) * 16; // + kt*128

  // Q B-frag: col=l15 (q=w*16+l15), k = 32c + l4*8 + j
  bf16x8 qf[2];
#pragma unroll
  for (int c = 0; c < 2; ++c)
    qf[c] = *(const bf16x8*)(Qg + (size_t)(w * 16 + l15) * HD + c * 32 + l4 * 8);

  const bf16x4 ones4 = {(short)0x3F80, (short)0x3F80, (short)0x3F80, (short)0x3F80};

  f32x4 of[4];
#pragma unroll
  for (int dt = 0; dt < 4; ++dt)
#pragma unroll
    for (int j = 0; j < 4; ++j) of[dt][j] = 0.f;
  f32x4 rs = {0.f, 0.f, 0.f, 0.f};   // cross-tile row-sum accumulator
  float negm = 0.f;                  // = -m (defer-max reference)
  f32x4 negm4 = {0.f, 0.f, 0.f, 0.f};   // persistent QK C-in seed

  int q = qb * 256 + w * 16 + l15;

  auto STAGE = [&](int b, int kt) {
    if (w < 8) load_lds_16B(gk0 + (size_t)kt * 8192, (char*)&Kt[b][0] + w * 1024);
    else       load_lds_16B(gv0 + (size_t)kt * 128, (char*)&Vt[b][0] + (w - 8) * 1024);
  };

  // PV A-frag granule offsets: byte = row*128 + ((ct*4+l4)^l15)*8
  int voff[4];
#pragma unroll
  for (int ct = 0; ct < 4; ++ct)
    voff[ct] = (((ct * 4 + l4) ^ l15) * 8);

  // prologue
  const u64* mptr = mbits + (size_t)n * 32 * 2048 + q;
  STAGE(0, 0);
  u64 mw = mptr[0];
  asm volatile("s_waitcnt vmcnt(0)" ::: "memory");
  __syncthreads();

#pragma unroll 2
  for (int kt = 0; kt < NT; ++kt) {
    int cur = kt & 1;
    u64 mw_nxt = 0;
    if (kt < NT - 1) {
      STAGE(cur ^ 1, kt + 1);
      mw_nxt = mptr[(size_t)(kt + 1) * 2048];   // prefetch next tile's mask word
    }
    const char* KB = (const char*)&Kt[cur][0];
    const char* VB = (const char*)&Vt[cur][0];

    // ---- S^T = K Q^T; C-in = negm4 (persistent) => sf = s - m after MFMA
    f32x4 sf[4];
#pragma unroll
    for (int ct = 0; ct < 4; ++ct) {
      int krow = ct * 16 + l15;
      bf16x8 ak = *(const bf16x8*)(KB + krow * 128 + ((l4 ^ e7) * 16));
      sf[ct] = __builtin_amdgcn_mfma_f32_16x16x32_bf16(ak, qf[0], negm4, 0, 0, 0);
    }
#pragma unroll
    for (int ct = 0; ct < 4; ++ct) {
      int krow = ct * 16 + l15;
      bf16x8 ak = *(const bf16x8*)(KB + krow * 128 + (((4 + l4) ^ e7) * 16));
      sf[ct] = __builtin_amdgcn_mfma_f32_16x16x32_bf16(ak, qf[1], sf[ct], 0, 0, 0);
    }

    // ---- defer-max: rescale only if some lane's tile max exceeds THR=8
    float t0 = m3(sf[0][0], sf[0][1], sf[0][2]);
    float t1 = m3(sf[0][3], sf[1][0], sf[1][1]);
    float t2 = m3(sf[1][2], sf[1][3], sf[2][0]);
    float t3 = m3(sf[2][1], sf[2][2], sf[2][3]);
    float t4 = m3(sf[3][0], sf[3][1], sf[3][2]);
    float tmax = fmaxf(m3(t0, t1, t2), m3(t3, t4, sf[3][3]));
    if (__any(tmax > 8.f)) {
      float tm = fmaxf(tmax, __shfl_xor(tmax, 16));
      tm = fmaxf(tm, __shfl_xor(tm, 32));
      float d = fmaxf(tm, 0.f);                 // per-q delta (0 if no new max)
      float corr = __builtin_amdgcn_exp2f(-d);
      negm -= d;
      negm4[0] = negm; negm4[1] = negm; negm4[2] = negm; negm4[3] = negm;
#pragma unroll
      for (int j = 0; j < 4; ++j) rs[j] *= corr;
#pragma unroll
      for (int dt = 0; dt < 4; ++dt)
#pragma unroll
        for (int r = 0; r < 4; ++r) of[dt][r] *= corr;
#pragma unroll
      for (int ct = 0; ct < 4; ++ct)
#pragma unroll
        for (int r = 0; r < 4; ++r) sf[ct][r] -= d;
    }
    // ---- p = exp2(sf) (<= 2^8), mask-zero (bit 16ct + 4*l4 + r), pack to bf16
    u64 m4 = mw >> (l4 * 4);
    u32 c0 = (u32)m4, c1 = (u32)(m4 >> 32);
    bf16x4 pbq[4];
#pragma unroll
    for (int ct = 0; ct < 4; ++ct) {
      u32 sel = (ct & 2) ? c1 : c0;
      u32 base = (ct & 1) ? 0x10000u : 1u;
      float p0 = __builtin_amdgcn_exp2f(sf[ct][0]);
      float p1 = __builtin_amdgcn_exp2f(sf[ct][1]);
      float p2 = __builtin_amdgcn_exp2f(sf[ct][2]);
      float p3 = __builtin_amdgcn_exp2f(sf[ct][3]);
      p0 = (sel & (base << 0)) ? p0 : 0.f;
      p1 = (sel & (base << 1)) ? p1 : 0.f;
      p2 = (sel & (base << 2)) ? p2 : 0.f;
      p3 = (sel & (base << 3)) ? p3 : 0.f;
      union { u32 u[2]; bf16x4 s; } pu;
      pu.u[0] = pk2(p0, p1);
      pu.u[1] = pk2(p2, p3);
      pbq[ct] = pu.s;
    }
    // ---- row-sum accumulates across tiles (A = ones => all C rows identical)
#pragma unroll
    for (int ct = 0; ct < 4; ++ct)
      rs = __builtin_amdgcn_mfma_f32_16x16x16bf16_1k(ones4, pbq[ct], rs, 0, 0, 0);
    // ---- O^T += V^T P : A = V^T b64 granule frags (conflict-free), B = register P
#pragma unroll
    for (int dt = 0; dt < 4; ++dt) {
      int vrow_b = (dt * 16 + l15) * 128;
#pragma unroll
      for (int ct = 0; ct < 4; ++ct) {
        bf16x4 av = *(const bf16x4*)(VB + vrow_b + voff[ct]);
        of[dt] = __builtin_amdgcn_mfma_f32_16x16x16bf16_1k(av, pbq[ct], of[dt], 0, 0, 0);
      }
    }

    mw = mw_nxt;
    if (kt < NT - 1) {
      asm volatile("s_waitcnt vmcnt(0)" ::: "memory");   // next-tile stage landed
      __syncthreads();
    }
  }
  // ---- epilogue: lane owns q; d = 16dt + 4*l4 + r (8B packed stores)
  float inv = 1.f / rs[0];
  size_t obase = ((size_t)n * SEQ + q) * EMB + h * HD;
#pragma unroll
  for (int dt = 0; dt < 4; ++dt) {
    uint2 v2 = {pk2(of[dt][0] * inv, of[dt][1] * inv),
                pk2(of[dt][2] * inv, of[dt][3] * inv)};
    *(uint2*)(obuf + obase + dt * 16 + l4 * 4) = v2;
  }
}

// ---------------- output GEMM: double-buffered, chunk-swizzled ----------------
__global__ __launch_bounds__(256) void out_gemm_k(const __hip_bfloat16* __restrict__ A,
                                                  const __hip_bfloat16* __restrict__ Bw,
                                                  const float* __restrict__ bias,
                                                  float* __restrict__ Y) {
  __shared__ __align__(16) __hip_bfloat16 As[2][128 * 32];
  __shared__ __align__(16) __hip_bfloat16 Bs[2][128 * 32];
  int t = threadIdx.x, lane = t & 63, w = t >> 6;
  int l15 = lane & 15, l4 = lane >> 4;
  int bm = blockIdx.x * 128, bn = blockIdx.y * 128;
  int wr = w >> 1, wc = w & 1;
  f32x4 acc[4][4];
#pragma unroll
  for (int m = 0; m < 4; ++m)
#pragma unroll
    for (int nn = 0; nn < 4; ++nn)
#pragma unroll
      for (int j = 0; j < 4; ++j) acc[m][nn][j] = 0.f;

  int srow = t >> 2;                        // LDS row 0..63 (row stride 64B)
  int schunk = (t & 3) ^ (srow & 3);        // source 16B chunk pre-swizzle

  auto STAGE = [&](int b, int kt) {
    const char* ga = (const char*)(A + (size_t)(bm + srow) * 1024 + kt * 32) + schunk * 16;
    char* da = (char*)&As[b][0] + w * 1024;
    load_lds_16B(ga, da);
    load_lds_16B(ga + (size_t)64 * 2048, da + 4096);   // rows +64: same (row&3)
    const char* gb = (const char*)(Bw + (size_t)(bn + srow) * 1024 + kt * 32) + schunk * 16;
    char* db = (char*)&Bs[b][0] + w * 1024;
    load_lds_16B(gb, db);
    load_lds_16B(gb + (size_t)64 * 2048, db + 4096);
  };

  STAGE(0, 0);
  asm volatile("s_waitcnt vmcnt(0)" ::: "memory");
  __syncthreads();

#pragma unroll 2
  for (int kt = 0; kt < 32; ++kt) {
    int cur = kt & 1;
    if (kt < 31) STAGE(cur ^ 1, kt + 1);
    const char* AB = (const char*)&As[cur][0];
    const char* BB = (const char*)&Bs[cur][0];
    bf16x8 af[4], bfr[4];
#pragma unroll
    for (int m = 0; m < 4; ++m) {
      int arow = wr * 64 + m * 16 + l15;
      af[m] = *(const bf16x8*)(AB + arow * 64 + ((l4 ^ (arow & 3)) * 16));
    }
#pragma unroll
    for (int nn = 0; nn < 4; ++nn) {
      int brow = wc * 64 + nn * 16 + l15;
      bfr[nn] = *(const bf16x8*)(BB + brow * 64 + ((l4 ^ (brow & 3)) * 16));
    }
#pragma unroll
    for (int m = 0; m < 4; ++m)
#pragma unroll
      for (int nn = 0; nn < 4; ++nn)
        acc[m][nn] = __builtin_amdgcn_mfma_f32_16x16x32_bf16(af[m], bfr[nn], acc[m][nn], 0, 0, 0);
    if (kt < 31) {
      asm volatile("s_waitcnt vmcnt(0)" ::: "memory");
      __syncthreads();
    }
  }
#pragma unroll
  for (int m = 0; m < 4; ++m)
#pragma unroll
    for (int nn = 0; nn < 4; ++nn)
#pragma unroll
      for (int r = 0; r < 4; ++r) {
        int row = bm + wr * 64 + m * 16 + l4 * 4 + r;
        int col = bn + wc * 64 + nn * 16 + l15;
        Y[(size_t)row * 1024 + col] = acc[m][nn][r] + bias[col];
      }
}

extern "C" void kernel_launch(void* const* d_in, const int* in_sizes, int n_in,
                              void* d_out, int out_size, void* d_ws, size_t ws_size,
                              hipStream_t stream) {
  const float* values  = (const float*)d_in[0];
  const float* keys    = (const float*)d_in[1];
  const float* queries = (const float*)d_in[2];
  const int*   mask    = (const int*)d_in[3];
  const float* Wv      = (const float*)d_in[4];
  const float* Wk      = (const float*)d_in[5];
  const float* Wq      = (const float*)d_in[6];
  const float* Wo      = (const float*)d_in[7];
  const float* bo      = (const float*)d_in[8];
  float* out = (float*)d_out;

  char* ws = (char*)d_ws;
  __hip_bfloat16* qp   = (__hip_bfloat16*)(ws);
  __hip_bfloat16* kp   = (__hip_bfloat16*)(ws + (size_t)16 * 1024 * 1024);
  __hip_bfloat16* obuf = (__hip_bfloat16*)(ws + (size_t)48 * 1024 * 1024);
  u64*            mbts = (u64*)           (ws + (size_t)64 * 1024 * 1024);
  __hip_bfloat16* wob  = (__hip_bfloat16*)(ws + (size_t)66 * 1024 * 1024);
  __hip_bfloat16* vTp  = (__hip_bfloat16*)(ws + (size_t)80 * 1024 * 1024);

  // Q pre-scale: (1/sqrt(EMB)) * log2(e) so attn softmax runs in exp2 domain
  const float qscale = 0.03125f * 1.44269504088896340736f;

  fused_pre_k<<<dim3(SEQ / 64, NH, 17), 256, 0, stream>>>(values, keys, queries,
                                                          Wv, Wk, Wq, vTp, kp, qp,
                                                          mask, mbts, Wo, wob, qscale);
  attn_k<<<dim3(8, 64), 1024, 0, stream>>>(qp, kp, vTp, mbts, obuf);
  out_gemm_k<<<dim3(64, 8), 256, 0, stream>>>(obuf, wob, bo, out);
}

// Round 22
// 183.332 us; speedup vs baseline: 1.0180x; 1.0180x over previous
//
#include <hip/hip_runtime.h>
#include <hip/hip_bf16.h>

#define N_B 4
#define SEQ 2048
#define EMB 1024
#define NH  16
#define HD  64
#define NT  (SEQ / 64)

typedef __attribute__((ext_vector_type(8))) short bf16x8;   // 8 bf16 in 4 VGPRs
typedef __attribute__((ext_vector_type(4))) short bf16x4;   // 4 bf16 in 2 VGPRs
typedef __attribute__((ext_vector_type(4))) float f32x4;
typedef unsigned int u32;
typedef unsigned long long u64;
typedef unsigned short u16;

__device__ __forceinline__ void load_lds_16B(const void* g, void* lds) {
  __builtin_amdgcn_global_load_lds(
      (const __attribute__((address_space(1))) u32*)g,
      (__attribute__((address_space(3))) u32*)lds, 16, 0, 0);
}

// pack two f32 -> two bf16 (round-to-nearest via +0x8000 before truncate)
__device__ __forceinline__ u32 pk2(float a, float b) {
  u32 au = __float_as_uint(a) + 0x8000u;
  u32 bu = __float_as_uint(b) + 0x8000u;
  return (au >> 16) | (bu & 0xFFFF0000u);
}

__device__ __forceinline__ float m3(float a, float b, float c) {
  return fmaxf(fmaxf(a, b), c);   // clang fuses to v_max3_f32
}

// ---------------- unified MFMA pre-pass (R19-proven) ----------------
// grid (32, 16, 17):
//   z in [0,4): mask->bitmask pack, 2048 blocks x 4 rows (batched-load TLP).
//   z == 4: Wo fp32->bf16 cvt.
//   z in [5,17): projection, which = (z-5)>>2 (0=v,1=k,2=q), n = (z-5)&3.
__global__ __launch_bounds__(256) void fused_pre_k(const float* __restrict__ xv,
                                                   const float* __restrict__ xk,
                                                   const float* __restrict__ xq,
                                                   const float* __restrict__ Wv,
                                                   const float* __restrict__ Wk,
                                                   const float* __restrict__ Wq,
                                                   __hip_bfloat16* __restrict__ vT,
                                                   __hip_bfloat16* __restrict__ kp,
                                                   __hip_bfloat16* __restrict__ qp,
                                                   const int* __restrict__ mask,
                                                   u64* __restrict__ bits,
                                                   const float* __restrict__ Wo,
                                                   __hip_bfloat16* __restrict__ wob,
                                                   float qscale) {
  int z = blockIdx.z;
  int t = threadIdx.x;
  if (z < 4) {                         // ---- mask pack (4 rows, batched loads)
    int flat = (z * 16 + blockIdx.y) * 32 + blockIdx.x;   // 0..2047
    int lane = t & 63, wv = t >> 6;
    int row0 = flat * 4;
    for (int w = wv; w < 32; w += 4) {
      int v0 = mask[(size_t)(row0 + 0) * SEQ + w * 64 + lane];
      int v1 = mask[(size_t)(row0 + 1) * SEQ + w * 64 + lane];
      int v2 = mask[(size_t)(row0 + 2) * SEQ + w * 64 + lane];
      int v3 = mask[(size_t)(row0 + 3) * SEQ + w * 64 + lane];
      u64 b0 = __ballot(v0 != 0);
      u64 b1 = __ballot(v1 != 0);
      u64 b2 = __ballot(v2 != 0);
      u64 b3 = __ballot(v3 != 0);
      if (lane == 0) {
        int n = row0 >> 11;                       // 4 rows never straddle n
        size_t base = ((size_t)n * 32 + w) * 2048 + (row0 & 2047);
        bits[base + 0] = b0;
        bits[base + 1] = b1;
        bits[base + 2] = b2;
        bits[base + 3] = b3;
      }
    }
    return;
  }
  if (z == 4) {                        // ---- Wo cvt
    int flat = blockIdx.y * 32 + blockIdx.x;   // 0..511
#pragma unroll
    for (int k = 0; k < 2; ++k) {
      int f4i = flat * 512 + k * 256 + t;
      float4 v = ((const float4*)Wo)[f4i];
      int i = f4i * 4;
      wob[i + 0] = __float2bfloat16(v.x);
      wob[i + 1] = __float2bfloat16(v.y);
      wob[i + 2] = __float2bfloat16(v.z);
      wob[i + 3] = __float2bfloat16(v.w);
    }
    return;
  }
  // ---- projection
  int zz = z - 5;
  int which = zz >> 2, n = zz & 3;
  int kt = blockIdx.x, h = blockIdx.y;
  const float* x = (which == 0) ? xv : (which == 1) ? xk : xq;
  const float* W = (which == 0) ? Wv : (which == 1) ? Wk : Wq;
  float wscale = (which == 2) ? qscale : 1.0f;
  __shared__ __align__(16) __hip_bfloat16 Xs[64 * 64];   // [row][dd] chunk-swz
  __shared__ __align__(16) __hip_bfloat16 Ws[64 * 64];   // [d][dd]   chunk-swz

  int tr = t >> 4, c4 = t & 15;
  const float4* x4 = (const float4*)x;
#pragma unroll
  for (int i = 0; i < 4; ++i) {
    int r = i * 16 + tr;
    float4 v = x4[((size_t)(n * SEQ + kt * 64 + r)) * 256 + h * 16 + c4];
    uint2 pv = {pk2(v.x, v.y), pk2(v.z, v.w)};
    *(uint2*)((char*)Xs + r * 128 + (((c4 >> 1) ^ (r & 7)) * 16) + (c4 & 1) * 8) = pv;
  }
  const float4* W4 = (const float4*)W;
#pragma unroll
  for (int i = 0; i < 4; ++i) {
    int d = i * 16 + tr, dd4 = c4;
    float4 v = W4[(size_t)d * 16 + dd4];
    uint2 pv = {pk2(v.x * wscale, v.y * wscale), pk2(v.z * wscale, v.w * wscale)};
    *(uint2*)((char*)Ws + d * 128 + (((dd4 >> 1) ^ (d & 7)) * 16) + (dd4 & 1) * 8) = pv;
  }
  __syncthreads();

  int lane = t & 63, w = t >> 6;
  int l15 = lane & 15, l4 = lane >> 4, e7 = l15 & 7;
  bf16x8 xa0 = *(const bf16x8*)((char*)Xs + (w * 16 + l15) * 128 + ((l4 ^ e7) * 16));
  bf16x8 xa1 = *(const bf16x8*)((char*)Xs + (w * 16 + l15) * 128 + (((4 + l4) ^ e7) * 16));
  if (which == 0) {
    // ---- V: D[seq][d]; packed uint2 store per dt into vT granule-perm layout
    u16* dst = (u16*)(vT + (size_t)(n * NH + h) * HD * SEQ);
#pragma unroll
    for (int dt = 0; dt < 4; ++dt) {
      bf16x8 wb0 = *(const bf16x8*)((char*)Ws + (dt * 16 + l15) * 128 + ((l4 ^ e7) * 16));
      bf16x8 wb1 = *(const bf16x8*)((char*)Ws + (dt * 16 + l15) * 128 + (((4 + l4) ^ e7) * 16));
      f32x4 c = {0.f, 0.f, 0.f, 0.f};
      c = __builtin_amdgcn_mfma_f32_16x16x32_bf16(xa0, wb0, c, 0, 0, 0);
      c = __builtin_amdgcn_mfma_f32_16x16x32_bf16(xa1, wb1, c, 0, 0, 0);
      int d = dt * 16 + l15;
      int slotbase = kt * 64 + (((w * 4 + l4) ^ l15) * 4);
      uint2 pv = {pk2(c[0], c[1]), pk2(c[2], c[3])};
      *(uint2*)(dst + (size_t)d * SEQ + slotbase) = pv;
    }
  } else {
    // ---- K/Q: swapped operands -> D[d][seq]; packed uint2 store per dt
    __hip_bfloat16* out = (which == 1) ? kp : qp;
    u16* orow = (u16*)(out + ((size_t)(n * NH + h) * SEQ + kt * 64 + w * 16 + l15) * HD);
#pragma unroll
    for (int dt = 0; dt < 4; ++dt) {
      bf16x8 wb0 = *(const bf16x8*)((char*)Ws + (dt * 16 + l15) * 128 + ((l4 ^ e7) * 16));
      bf16x8 wb1 = *(const bf16x8*)((char*)Ws + (dt * 16 + l15) * 128 + (((4 + l4) ^ e7) * 16));
      f32x4 c = {0.f, 0.f, 0.f, 0.f};
      c = __builtin_amdgcn_mfma_f32_16x16x32_bf16(wb0, xa0, c, 0, 0, 0);
      c = __builtin_amdgcn_mfma_f32_16x16x32_bf16(wb1, xa1, c, 0, 0, 0);
      uint2 pv = {pk2(c[0], c[1]), pk2(c[2], c[3])};
      *(uint2*)(orow + dt * 16 + l4 * 4) = pv;
    }
  }
}

// ---------------- flash attention (8-wave blocks, QBLK=128; R20-proven) ----------------
// Same per-wave structure as the proven R13/R16 kernel; 8 waves share each
// staged K/V tile (LDS 32KB dbuf) -> 2 blocks/CU = 16 waves/CU.
__global__ __launch_bounds__(512) void attn_k(const __hip_bfloat16* __restrict__ qp,
                                              const __hip_bfloat16* __restrict__ kp,
                                              const __hip_bfloat16* __restrict__ vT,
                                              const u64* __restrict__ mbits,
                                              __hip_bfloat16* __restrict__ obuf) {
  __shared__ __align__(16) __hip_bfloat16 Kt[2][64 * 64];    // [key][kdim] chunk-swz
  __shared__ __align__(16) __hip_bfloat16 Vt[2][64 * 64];    // [d][key] granule-swz
  int t = threadIdx.x, lane = t & 63, w = t >> 6;            // w in [0,8)
  // XCD swizzle (bijective rotation; XCD a -> heads [8a, 8a+8))
  int flat = blockIdx.y * 16 + blockIdx.x;                   // 0..1023
  int nf = (flat & 7) * 128 + (flat >> 3);
  int qb = nf & 15, nh = nf >> 4;                            // qb: 128-row block
  int n = nh >> 4, h = nh & 15;
  const __hip_bfloat16* Qg = qp + ((size_t)nh * SEQ + qb * 128) * HD;
  const char* Kg = (const char*)(kp + (size_t)nh * SEQ * HD);
  const char* Vg = (const char*)(vT + (size_t)nh * HD * SEQ);
  int l15 = lane & 15, l4 = lane >> 4;
  int e7 = l15 & 7;

  int srow = t >> 3;                       // 0..63 across 512 threads
  int schunk = (t & 7) ^ (srow & 7);       // source pre-swizzle (16B chunks)

  // Q B-frag: col=l15 (q=w*16+l15), k = 32c + l4*8 + j
  bf16x8 qf[2];
#pragma unroll
  for (int c = 0; c < 2; ++c)
    qf[c] = *(const bf16x8*)(Qg + (size_t)(w * 16 + l15) * HD + c * 32 + l4 * 8);

  const bf16x4 ones4 = {(short)0x3F80, (short)0x3F80, (short)0x3F80, (short)0x3F80};

  f32x4 of[4];
#pragma unroll
  for (int dt = 0; dt < 4; ++dt)
#pragma unroll
    for (int j = 0; j < 4; ++j) of[dt][j] = 0.f;
  f32x4 rs = {0.f, 0.f, 0.f, 0.f};   // cross-tile row-sum accumulator
  float negm = 0.f;                  // = -m (defer-max reference)
  f32x4 negm4 = {0.f, 0.f, 0.f, 0.f};   // persistent QK C-in seed

  int q = qb * 128 + w * 16 + l15;

  // staging base pointers: 512 threads stage one 8KB K + one 8KB V per tile
  const char* gk0 = Kg + srow * 128 + schunk * 16;            // + kt*8192
  const char* gv0 = Vg + (size_t)srow * 4096 + (t & 7) * 16;  // + kt*128

  auto STAGE = [&](int b, int kt) {
    load_lds_16B(gk0 + (size_t)kt * 8192, (char*)&Kt[b][0] + w * 1024);
    load_lds_16B(gv0 + (size_t)kt * 128, (char*)&Vt[b][0] + w * 1024);
  };

  // PV A-frag granule offsets: byte = row*128 + ((ct*4+l4)^l15)*8
  int voff[4];
#pragma unroll
  for (int ct = 0; ct < 4; ++ct)
    voff[ct] = (((ct * 4 + l4) ^ l15) * 8);

  // prologue
  const u64* mptr = mbits + (size_t)n * 32 * 2048 + q;
  STAGE(0, 0);
  u64 mw = mptr[0];
  asm volatile("s_waitcnt vmcnt(0)" ::: "memory");
  __syncthreads();

#pragma unroll 2
  for (int kt = 0; kt < NT; ++kt) {
    int cur = kt & 1;
    u64 mw_nxt = 0;
    if (kt < NT - 1) {
      STAGE(cur ^ 1, kt + 1);
      mw_nxt = mptr[(size_t)(kt + 1) * 2048];   // prefetch next tile's mask word
    }
    const char* KB = (const char*)&Kt[cur][0];
    const char* VB = (const char*)&Vt[cur][0];

    // ---- S^T = K Q^T; C-in = negm4 (persistent) => sf = s - m after MFMA
    f32x4 sf[4];
#pragma unroll
    for (int ct = 0; ct < 4; ++ct) {
      int krow = ct * 16 + l15;
      bf16x8 ak = *(const bf16x8*)(KB + krow * 128 + ((l4 ^ e7) * 16));
      sf[ct] = __builtin_amdgcn_mfma_f32_16x16x32_bf16(ak, qf[0], negm4, 0, 0, 0);
    }
#pragma unroll
    for (int ct = 0; ct < 4; ++ct) {
      int krow = ct * 16 + l15;
      bf16x8 ak = *(const bf16x8*)(KB + krow * 128 + (((4 + l4) ^ e7) * 16));
      sf[ct] = __builtin_amdgcn_mfma_f32_16x16x32_bf16(ak, qf[1], sf[ct], 0, 0, 0);
    }

    // ---- defer-max: rescale only if some lane's tile max exceeds THR=8
    float t0 = m3(sf[0][0], sf[0][1], sf[0][2]);
    float t1 = m3(sf[0][3], sf[1][0], sf[1][1]);
    float t2 = m3(sf[1][2], sf[1][3], sf[2][0]);
    float t3 = m3(sf[2][1], sf[2][2], sf[2][3]);
    float t4 = m3(sf[3][0], sf[3][1], sf[3][2]);
    float tmax = fmaxf(m3(t0, t1, t2), m3(t3, t4, sf[3][3]));
    if (__any(tmax > 8.f)) {
      float tm = fmaxf(tmax, __shfl_xor(tmax, 16));
      tm = fmaxf(tm, __shfl_xor(tm, 32));
      float d = fmaxf(tm, 0.f);                 // per-q delta (0 if no new max)
      float corr = __builtin_amdgcn_exp2f(-d);
      negm -= d;
      negm4[0] = negm; negm4[1] = negm; negm4[2] = negm; negm4[3] = negm;
#pragma unroll
      for (int j = 0; j < 4; ++j) rs[j] *= corr;
#pragma unroll
      for (int dt = 0; dt < 4; ++dt)
#pragma unroll
        for (int r = 0; r < 4; ++r) of[dt][r] *= corr;
#pragma unroll
      for (int ct = 0; ct < 4; ++ct)
#pragma unroll
        for (int r = 0; r < 4; ++r) sf[ct][r] -= d;
    }
    // ---- p = exp2(sf) (<= 2^8), mask-zero (bit 16ct + 4*l4 + r), pack to bf16
    u64 m4 = mw >> (l4 * 4);
    u32 c0 = (u32)m4, c1 = (u32)(m4 >> 32);
    bf16x4 pbq[4];
#pragma unroll
    for (int ct = 0; ct < 4; ++ct) {
      u32 sel = (ct & 2) ? c1 : c0;
      u32 base = (ct & 1) ? 0x10000u : 1u;
      float p0 = __builtin_amdgcn_exp2f(sf[ct][0]);
      float p1 = __builtin_amdgcn_exp2f(sf[ct][1]);
      float p2 = __builtin_amdgcn_exp2f(sf[ct][2]);
      float p3 = __builtin_amdgcn_exp2f(sf[ct][3]);
      p0 = (sel & (base << 0)) ? p0 : 0.f;
      p1 = (sel & (base << 1)) ? p1 : 0.f;
      p2 = (sel & (base << 2)) ? p2 : 0.f;
      p3 = (sel & (base << 3)) ? p3 : 0.f;
      union { u32 u[2]; bf16x4 s; } pu;
      pu.u[0] = pk2(p0, p1);
      pu.u[1] = pk2(p2, p3);
      pbq[ct] = pu.s;
    }
    // ---- row-sum accumulates across tiles (A = ones => all C rows identical)
#pragma unroll
    for (int ct = 0; ct < 4; ++ct)
      rs = __builtin_amdgcn_mfma_f32_16x16x16bf16_1k(ones4, pbq[ct], rs, 0, 0, 0);
    // ---- O^T += V^T P : A = V^T b64 granule frags (conflict-free), B = register P
#pragma unroll
    for (int dt = 0; dt < 4; ++dt) {
      int vrow_b = (dt * 16 + l15) * 128;
#pragma unroll
      for (int ct = 0; ct < 4; ++ct) {
        bf16x4 av = *(const bf16x4*)(VB + vrow_b + voff[ct]);
        of[dt] = __builtin_amdgcn_mfma_f32_16x16x16bf16_1k(av, pbq[ct], of[dt], 0, 0, 0);
      }
    }

    mw = mw_nxt;
    if (kt < NT - 1) {
      asm volatile("s_waitcnt vmcnt(0)" ::: "memory");   // next-tile stage landed
      __syncthreads();
    }
  }
  // ---- epilogue: lane owns q; d = 16dt + 4*l4 + r (8B packed stores)
  float inv = 1.f / rs[0];
  size_t obase = ((size_t)n * SEQ + q) * EMB + h * HD;
#pragma unroll
  for (int dt = 0; dt < 4; ++dt) {
    uint2 v2 = {pk2(of[dt][0] * inv, of[dt][1] * inv),
                pk2(of[dt][2] * inv, of[dt][3] * inv)};
    *(uint2*)(obuf + obase + dt * 16 + l4 * 4) = v2;
  }
}

// ---------------- output GEMM: double-buffered, chunk-swizzled ----------------
__global__ __launch_bounds__(256) void out_gemm_k(const __hip_bfloat16* __restrict__ A,
                                                  const __hip_bfloat16* __restrict__ Bw,
                                                  const float* __restrict__ bias,
                                                  float* __restrict__ Y) {
  __shared__ __align__(16) __hip_bfloat16 As[2][128 * 32];
  __shared__ __align__(16) __hip_bfloat16 Bs[2][128 * 32];
  int t = threadIdx.x, lane = t & 63, w = t >> 6;
  int l15 = lane & 15, l4 = lane >> 4;
  int bm = blockIdx.x * 128, bn = blockIdx.y * 128;
  int wr = w >> 1, wc = w & 1;
  f32x4 acc[4][4];
#pragma unroll
  for (int m = 0; m < 4; ++m)
#pragma unroll
    for (int nn = 0; nn < 4; ++nn)
#pragma unroll
      for (int j = 0; j < 4; ++j) acc[m][nn][j] = 0.f;

  int srow = t >> 2;                        // LDS row 0..63 (row stride 64B)
  int schunk = (t & 3) ^ (srow & 3);        // source 16B chunk pre-swizzle

  auto STAGE = [&](int b, int kt) {
    const char* ga = (const char*)(A + (size_t)(bm + srow) * 1024 + kt * 32) + schunk * 16;
    char* da = (char*)&As[b][0] + w * 1024;
    load_lds_16B(ga, da);
    load_lds_16B(ga + (size_t)64 * 2048, da + 4096);   // rows +64: same (row&3)
    const char* gb = (const char*)(Bw + (size_t)(bn + srow) * 1024 + kt * 32) + schunk * 16;
    char* db = (char*)&Bs[b][0] + w * 1024;
    load_lds_16B(gb, db);
    load_lds_16B(gb + (size_t)64 * 2048, db + 4096);
  };

  STAGE(0, 0);
  asm volatile("s_waitcnt vmcnt(0)" ::: "memory");
  __syncthreads();

#pragma unroll 2
  for (int kt = 0; kt < 32; ++kt) {
    int cur = kt & 1;
    if (kt < 31) STAGE(cur ^ 1, kt + 1);
    const char* AB = (const char*)&As[cur][0];
    const char* BB = (const char*)&Bs[cur][0];
    bf16x8 af[4], bfr[4];
#pragma unroll
    for (int m = 0; m < 4; ++m) {
      int arow = wr * 64 + m * 16 + l15;
      af[m] = *(const bf16x8*)(AB + arow * 64 + ((l4 ^ (arow & 3)) * 16));
    }
#pragma unroll
    for (int nn = 0; nn < 4; ++nn) {
      int brow = wc * 64 + nn * 16 + l15;
      bfr[nn] = *(const bf16x8*)(BB + brow * 64 + ((l4 ^ (brow & 3)) * 16));
    }
#pragma unroll
    for (int m = 0; m < 4; ++m)
#pragma unroll
      for (int nn = 0; nn < 4; ++nn)
        acc[m][nn] = __builtin_amdgcn_mfma_f32_16x16x32_bf16(af[m], bfr[nn], acc[m][nn], 0, 0, 0);
    if (kt < 31) {
      asm volatile("s_waitcnt vmcnt(0)" ::: "memory");
      __syncthreads();
    }
  }
#pragma unroll
  for (int m = 0; m < 4; ++m)
#pragma unroll
    for (int nn = 0; nn < 4; ++nn)
#pragma unroll
      for (int r = 0; r < 4; ++r) {
        int row = bm + wr * 64 + m * 16 + l4 * 4 + r;
        int col = bn + wc * 64 + nn * 16 + l15;
        Y[(size_t)row * 1024 + col] = acc[m][nn][r] + bias[col];
      }
}

extern "C" void kernel_launch(void* const* d_in, const int* in_sizes, int n_in,
                              void* d_out, int out_size, void* d_ws, size_t ws_size,
                              hipStream_t stream) {
  const float* values  = (const float*)d_in[0];
  const float* keys    = (const float*)d_in[1];
  const float* queries = (const float*)d_in[2];
  const int*   mask    = (const int*)d_in[3];
  const float* Wv      = (const float*)d_in[4];
  const float* Wk      = (const float*)d_in[5];
  const float* Wq      = (const float*)d_in[6];
  const float* Wo      = (const float*)d_in[7];
  const float* bo      = (const float*)d_in[8];
  float* out = (float*)d_out;

  char* ws = (char*)d_ws;
  __hip_bfloat16* qp   = (__hip_bfloat16*)(ws);
  __hip_bfloat16* kp   = (__hip_bfloat16*)(ws + (size_t)16 * 1024 * 1024);
  __hip_bfloat16* obuf = (__hip_bfloat16*)(ws + (size_t)48 * 1024 * 1024);
  u64*            mbts = (u64*)           (ws + (size_t)64 * 1024 * 1024);
  __hip_bfloat16* wob  = (__hip_bfloat16*)(ws + (size_t)66 * 1024 * 1024);
  __hip_bfloat16* vTp  = (__hip_bfloat16*)(ws + (size_t)80 * 1024 * 1024);

  // Q pre-scale: (1/sqrt(EMB)) * log2(e) so attn softmax runs in exp2 domain
  const float qscale = 0.03125f * 1.44269504088896340736f;

  fused_pre_k<<<dim3(SEQ / 64, NH, 17), 256, 0, stream>>>(values, keys, queries,
                                                          Wv, Wk, Wq, vTp, kp, qp,
                                                          mask, mbts, Wo, wob, qscale);
  attn_k<<<dim3(16, 64), 512, 0, stream>>>(qp, kp, vTp, mbts, obuf);
  out_gemm_k<<<dim3(64, 8), 256, 0, stream>>>(obuf, wob, bo, out);
}